// Round 7
// baseline (145.068 us; speedup 1.0000x reference)
//
#include <hip/hip_runtime.h>
#include <stdint.h>

typedef __attribute__((ext_vector_type(8))) short short8;
typedef __attribute__((ext_vector_type(4))) float floatx4;
typedef __attribute__((ext_vector_type(16))) float floatx16;
typedef __attribute__((ext_vector_type(2))) unsigned int uintx2;
typedef unsigned short u16;
typedef unsigned int u32;

#define EDIM 128
#define FDIM 512
#define BM 64             // rows per block (two 32-row tiles per wave)
#define QSTR (EDIM + 8)   // 136 bf16 = 272 B row stride (16B aligned)
#define HSTR (128 + 8)    // 136 bf16

// round-to-nearest-even float -> bf16 (prep path)
__device__ __forceinline__ u32 f2bf_rne(float f) {
    u32 u = __builtin_bit_cast(u32, f);
    return (u + 0x7fffu + ((u >> 16) & 1u)) >> 16;
}
__device__ __forceinline__ u32 pk2bf(float lo, float hi) {
    return f2bf_rne(lo) | (f2bf_rne(hi) << 16);
}
// HW packed f32x2 -> bf16x2, RNE (main path)
__device__ __forceinline__ u32 cvtpk(float lo, float hi) {
    u32 r;
    asm("v_cvt_pk_bf16_f32 %0, %1, %2" : "=v"(r) : "v"(lo), "v"(hi));
    return r;
}

// Pre-swizzle W1/W2 to bf16 in MFMA A-fragment lane order:
//   W1s group g  = ft*512 + k*64 + lane   (16B per group)
//        holds W1[ft*32 + (lane&31)][k*16 + (lane>>5)*8 + j], j=0..7
//   W2s group g2 = (et*4+c)*512 + k*64 + lane
//        holds W2[et*32 + (lane&31)][c*128 + k*16 + (lane>>5)*8 + j]
// Also: cth[e] = cos(theta[e]) as f32 at wb + 2*FDIM*EDIM (u16 offset).
__global__ __launch_bounds__(256) void ffq_prep(const float* __restrict__ W1,
                                                const float* __restrict__ W2,
                                                const float* __restrict__ theta,
                                                u16* __restrict__ wb) {
    int g = blockIdx.x * 256 + threadIdx.x;   // 0..16383
    int lane = g & 63;
    int kk = (g >> 6) & 7;
    int idx = (g >> 9) & 15;
    int l31 = lane & 31, h5 = lane >> 5;
    if (g < 128) {
        float* cth = reinterpret_cast<float*>(wb + 2 * FDIM * EDIM);
        cth[g] = cosf(theta[g]);
    }
    const float* src;
    if (g < 8192) {
        src = W1 + (idx * 32 + l31) * EDIM + kk * 16 + h5 * 8;
    } else {
        int gg = idx >> 2, c = idx & 3;
        src = W2 + (gg * 32 + l31) * FDIM + c * 128 + kk * 16 + h5 * 8;
    }
    float4 v0 = *reinterpret_cast<const float4*>(src);
    float4 v1 = *reinterpret_cast<const float4*>(src + 4);
    uint4 p;
    p.x = pk2bf(v0.x, v0.y);
    p.y = pk2bf(v0.z, v0.w);
    p.z = pk2bf(v1.x, v1.y);
    p.w = pk2bf(v1.z, v1.w);
    reinterpret_cast<uint4*>(wb)[g] = p;
}

// Fused q = cos(x)*cos(theta); h = relu(q@W1^T); out = h@W2^T.
// 64 rows/block, 4 waves (gg = f-group / e-group). Each wave runs TWO
// independent accumulator chains (m-tiles 0-31 and 32-63), sharing every
// A-fragment load (R6's verified dual-chain scheme, mp removed).
// LDS = 34816 B -> 4 independent blocks/CU, so per-chunk barriers of one
// block overlap with MFMA/staging phases of three others on the same SIMDs.
__global__ __launch_bounds__(256, 4) void ffq_main(const float* __restrict__ x,
                                                   const u16* __restrict__ wb,
                                                   float* __restrict__ out) {
    __shared__ u16 qs[BM * QSTR];   // 17408 B
    __shared__ u16 hs[BM * HSTR];   // 17408 B (total 34816 -> 4 blocks/CU)

    const int t = threadIdx.x;
    const int lane = t & 63;
    const int gg = t >> 6;        // wave id 0..3 = f-group (GEMM1) / e-group (GEMM2)
    const int l31 = lane & 31;
    const int h5 = lane >> 5;     // half-wave 0/1

    const u16* W1s = wb;
    const u16* W2s = wb + FDIM * EDIM;
    const float* cth = reinterpret_cast<const float*>(wb + 2 * FDIM * EDIM);

    // ---- stage q = cos(x)*cos(theta) into LDS (bf16), coalesced ----
    {
        const float4* xin = reinterpret_cast<const float4*>(x) +
                            (size_t)blockIdx.x * (BM * EDIM / 4);
        const int et = (t & 31) * 4;  // e offset; same each r since 256 % 32 == 0
        float c0 = cth[et + 0];
        float c1 = cth[et + 1];
        float c2 = cth[et + 2];
        float c3 = cth[et + 3];
        #pragma unroll
        for (int r = 0; r < 8; ++r) {
            int i = t + 256 * r;   // float4 index within tile
            int m = i >> 5;        // row 0..63
            float4 v = xin[i];
            uintx2 p;
            p.x = pk2bf(__cosf(v.x) * c0, __cosf(v.y) * c1);
            p.y = pk2bf(__cosf(v.z) * c2, __cosf(v.w) * c3);
            *reinterpret_cast<uintx2*>(&qs[m * QSTR + et]) = p;
        }
    }
    __syncthreads();

    const floatx16 zero = {0.f,0.f,0.f,0.f,0.f,0.f,0.f,0.f,
                           0.f,0.f,0.f,0.f,0.f,0.f,0.f,0.f};
    floatx16 acc2[2] = {zero, zero};   // out^T tiles, rows {0,32}+l31

    const u16* w1l = W1s + lane * 8;
    const u16* w2l = W2s + lane * 8;
    // q/h B-frag bases for the two m-tiles
    const u16* qp0 = &qs[l31 * QSTR + h5 * 8];
    const u16* qp1 = qp0 + 32 * QSTR;
    const u16* hp0 = &hs[l31 * HSTR + h5 * 8];
    const u16* hp1 = hp0 + 32 * HSTR;

    #pragma unroll
    for (int c = 0; c < 4; ++c) {
        // ---- GEMM1: two 32x32 h^T tiles, shared A-frags, K = 128 ----
        floatx16 a1[2] = {zero, zero};
        const u16* w1p = w1l + (size_t)(c * 4 + gg) * 4096;
        #pragma unroll
        for (int k = 0; k < 8; ++k) {
            short8 a  = *reinterpret_cast<const short8*>(w1p + k * 512);
            short8 b0 = *reinterpret_cast<const short8*>(qp0 + k * 16);
            short8 b1 = *reinterpret_cast<const short8*>(qp1 + k * 16);
            a1[0] = __builtin_amdgcn_mfma_f32_32x32x16_bf16(a, b0, a1[0], 0, 0, 0);
            a1[1] = __builtin_amdgcn_mfma_f32_32x32x16_bf16(a, b1, a1[1], 0, 0, 0);
        }

        // relu + bf16 -> h. D: col m=l31, row f=(reg&3)+8*(reg>>2)+4*h5
        #pragma unroll
        for (int s = 0; s < 2; ++s) {
            const int hrow = (s * 32 + l31) * HSTR;
            #pragma unroll
            for (int rq = 0; rq < 4; ++rq) {
                const int fl = gg * 32 + rq * 8 + h5 * 4;
                uintx2 p;
                p.x = cvtpk(fmaxf(a1[s][rq * 4 + 0], 0.f), fmaxf(a1[s][rq * 4 + 1], 0.f));
                p.y = cvtpk(fmaxf(a1[s][rq * 4 + 2], 0.f), fmaxf(a1[s][rq * 4 + 3], 0.f));
                *reinterpret_cast<uintx2*>(&hs[hrow + fl]) = p;
            }
        }
        __syncthreads();   // h ready

        // ---- GEMM2: two out^T tiles += W2_tile x h^T, chunk K = 128 ----
        const u16* w2p = w2l + (size_t)(gg * 4 + c) * 4096;
        #pragma unroll
        for (int k = 0; k < 8; ++k) {
            short8 a  = *reinterpret_cast<const short8*>(w2p + k * 512);
            short8 b0 = *reinterpret_cast<const short8*>(hp0 + k * 16);
            short8 b1 = *reinterpret_cast<const short8*>(hp1 + k * 16);
            acc2[0] = __builtin_amdgcn_mfma_f32_32x32x16_bf16(a, b0, acc2[0], 0, 0, 0);
            acc2[1] = __builtin_amdgcn_mfma_f32_32x32x16_bf16(a, b1, acc2[1], 0, 0, 0);
        }
        __syncthreads();   // WAR: hs consumed, next chunk may overwrite
    }

    // ---- epilogue: D col m=l31, row e=gg*32+(reg&3)+8*(reg>>2)+4*h5 ----
    #pragma unroll
    for (int s = 0; s < 2; ++s) {
        float* op = out + (size_t)blockIdx.x * BM * EDIM +
                    (s * 32 + l31) * EDIM + gg * 32 + h5 * 4;
        #pragma unroll
        for (int rq = 0; rq < 4; ++rq) {
            floatx4 v;
            v[0] = acc2[s][rq * 4 + 0];
            v[1] = acc2[s][rq * 4 + 1];
            v[2] = acc2[s][rq * 4 + 2];
            v[3] = acc2[s][rq * 4 + 3];
            *reinterpret_cast<floatx4*>(op + rq * 8) = v;
        }
    }
}

extern "C" void kernel_launch(void* const* d_in, const int* in_sizes, int n_in,
                              void* d_out, int out_size, void* d_ws, size_t ws_size,
                              hipStream_t stream) {
    const float* x     = (const float*)d_in[0];  // [32,4096,128]
    const float* theta = (const float*)d_in[1];  // [128]
    const float* W1    = (const float*)d_in[2];  // [512,128]
    const float* W2    = (const float*)d_in[3];  // [128,512]
    u16* wb    = (u16*)d_ws;                     // 256 KB bf16 weights + cos(theta) table
    float* out = (float*)d_out;                  // [32,4096,128]

    ffq_prep<<<64, 256, 0, stream>>>(W1, W2, theta, wb);
    ffq_main<<<2048, 256, 0, stream>>>(x, wb, out);
}